// Round 2
// baseline (663.602 us; speedup 1.0000x reference)
//
#include <hip/hip_runtime.h>

#define Sn 1024
#define Dn 64

typedef short v8s __attribute__((ext_vector_type(8)));
typedef float v4f __attribute__((ext_vector_type(4)));

__device__ __forceinline__ unsigned short f2bf(float x) {
    union { float f; unsigned u; } v; v.f = x;
    return (unsigned short)((v.u + 0x7FFFu + ((v.u >> 16) & 1u)) >> 16);
}
__device__ __forceinline__ float bf2f(unsigned short h) {
    union { float f; unsigned u; } v; v.u = ((unsigned)h) << 16;
    return v.f;
}
__device__ __forceinline__ void split2(float x, unsigned short& h, unsigned short& l) {
    unsigned short hs = f2bf(x);
    float lo = x - bf2f(hs);
    h = hs; l = f2bf(lo);
}

// One block = 32 q-rows of one (b,h). 512 threads = 8 waves.
// Phase A: S = Q K^T via 3-term bf16-split MFMA, mask->exp, P(bf16)->LDS,
//          row sums in regs. Then normalized attn written once (fp32).
// Phase B: context = (P V) * inv via bf16 MFMA, V staged transposed per k-tile.
__global__ __launch_bounds__(512, 1) void fused_attn(
    const float* __restrict__ Q, const float* __restrict__ K,
    const float* __restrict__ V, const int* __restrict__ M,
    float* __restrict__ attnO, float* __restrict__ ctxO)
{
    __shared__ unsigned short Ph[32][1032];                 // P (exp, bf16), padded
    __shared__ __align__(16) unsigned char KVraw[36864];    // Khi/Klo, reused as Vt
    __shared__ unsigned short Qhi[32][72];
    __shared__ unsigned short Qlo[32][72];
    __shared__ float rsumW[8][32];
    __shared__ float invL[32];

    unsigned short (*Khi)[72] = (unsigned short (*)[72])KVraw;            // [128][72]
    unsigned short (*Klo)[72] = (unsigned short (*)[72])(KVraw + 18432);  // [128][72]
    unsigned short (*Vt)[152] = (unsigned short (*)[152])KVraw;           // [64][152]

    const int tid  = threadIdx.x;
    const int lane = tid & 63;
    const int w    = tid >> 6;    // wave 0..7
    const int fr   = lane & 15;
    const int g    = lane >> 4;   // 0..3

    const int bh = blockIdx.x >> 5;
    const int q0 = (blockIdx.x & 31) << 5;

    const float* Qb = Q + (size_t)bh * Sn * Dn + (size_t)q0 * Dn;
    const float* Kb = K + (size_t)bh * Sn * Dn;
    const float* Vb = V + (size_t)bh * Sn * Dn;
    const int*   Mb = M + (size_t)bh * Sn * Sn + (size_t)q0 * Sn;
    float*       Ab = attnO + (size_t)bh * Sn * Sn + (size_t)q0 * Sn;
    float*       Cb = ctxO  + (size_t)bh * Sn * Dn + (size_t)q0 * Dn;

    // ---- stage Q tile (32x64) as hi/lo bf16 ----
    {
        const int row = tid >> 4, c4 = (tid & 15) << 2;
        const float4 qv = *(const float4*)(Qb + (size_t)row * Dn + c4);
        ushort4 hv, lv;
        split2(qv.x, hv.x, lv.x); split2(qv.y, hv.y, lv.y);
        split2(qv.z, hv.z, lv.z); split2(qv.w, hv.w, lv.w);
        *(ushort4*)&Qhi[row][c4] = hv;
        *(ushort4*)&Qlo[row][c4] = lv;
    }
    __syncthreads();

    // Q fragments (held in regs for all of phase A)
    v8s qh[2][2], ql[2][2];
    #pragma unroll
    for (int qf = 0; qf < 2; ++qf)
        #pragma unroll
        for (int dh = 0; dh < 2; ++dh) {
            qh[qf][dh] = *(const v8s*)&Qhi[(qf << 4) + fr][(dh << 5) + (g << 3)];
            ql[qf][dh] = *(const v8s*)&Qlo[(qf << 4) + fr][(dh << 5) + (g << 3)];
        }

    float rs[2][4] = {{0.f,0.f,0.f,0.f},{0.f,0.f,0.f,0.f}};

    // ---- Phase A: k-tiles of 128 ----
    for (int kt = 0; kt < 8; ++kt) {
        const int kc = (kt << 7) + (w << 4) + fr;   // this wave's k column
        // issue mask loads early (independent of LDS)
        int mv[2][4];
        #pragma unroll
        for (int qf = 0; qf < 2; ++qf)
            #pragma unroll
            for (int r = 0; r < 4; ++r)
                mv[qf][r] = Mb[(size_t)((qf << 4) + (g << 2) + r) * Sn + kc];

        __syncthreads();  // prev tile's frag reads done
        // stage K tile (128x64) hi/lo
        #pragma unroll
        for (int i = 0; i < 4; ++i) {
            const int f = tid + (i << 9);
            const int row = f >> 4, c4 = (f & 15) << 2;
            const float4 kv = *(const float4*)(Kb + (size_t)((kt << 7) + row) * Dn + c4);
            ushort4 hv, lv;
            split2(kv.x, hv.x, lv.x); split2(kv.y, hv.y, lv.y);
            split2(kv.z, hv.z, lv.z); split2(kv.w, hv.w, lv.w);
            *(ushort4*)&Khi[row][c4] = hv;
            *(ushort4*)&Klo[row][c4] = lv;
        }
        __syncthreads();

        const int krow = (w << 4) + fr;
        const v8s kh0 = *(const v8s*)&Khi[krow][(g << 3)];
        const v8s kh1 = *(const v8s*)&Khi[krow][32 + (g << 3)];
        const v8s kl0 = *(const v8s*)&Klo[krow][(g << 3)];
        const v8s kl1 = *(const v8s*)&Klo[krow][32 + (g << 3)];

        #pragma unroll
        for (int qf = 0; qf < 2; ++qf) {
            v4f acc = {0.f, 0.f, 0.f, 0.f};
            acc = __builtin_amdgcn_mfma_f32_16x16x32_bf16(qh[qf][0], kh0, acc, 0, 0, 0);
            acc = __builtin_amdgcn_mfma_f32_16x16x32_bf16(qh[qf][1], kh1, acc, 0, 0, 0);
            acc = __builtin_amdgcn_mfma_f32_16x16x32_bf16(ql[qf][0], kh0, acc, 0, 0, 0);
            acc = __builtin_amdgcn_mfma_f32_16x16x32_bf16(ql[qf][1], kh1, acc, 0, 0, 0);
            acc = __builtin_amdgcn_mfma_f32_16x16x32_bf16(qh[qf][0], kl0, acc, 0, 0, 0);
            acc = __builtin_amdgcn_mfma_f32_16x16x32_bf16(qh[qf][1], kl1, acc, 0, 0, 0);
            #pragma unroll
            for (int r = 0; r < 4; ++r) {
                const float e = mv[qf][r] ? 1.0f : __expf(acc[r]);
                Ph[(qf << 4) + (g << 2) + r][kc] = f2bf(e);
                float s = e;
                s += __shfl_xor(s, 1); s += __shfl_xor(s, 2);
                s += __shfl_xor(s, 4); s += __shfl_xor(s, 8);
                rs[qf][r] += s;
            }
        }
    }

    // ---- combine row sums across waves ----
    if (fr == 0) {
        #pragma unroll
        for (int qf = 0; qf < 2; ++qf)
            #pragma unroll
            for (int r = 0; r < 4; ++r)
                rsumW[w][(qf << 4) + (g << 2) + r] = rs[qf][r];
    }
    __syncthreads();
    if (tid < 32) {
        float s = 0.f;
        #pragma unroll
        for (int ww = 0; ww < 8; ++ww) s += rsumW[ww][tid];
        invL[tid] = 1.0f / s;
    }
    __syncthreads();

    // ---- write normalized attn (fp32, coalesced) ----
    {
        const int qq = tid >> 4, ii = tid & 15;
        const float inv = invL[qq];
        float* arow = Ab + (size_t)qq * Sn;
        #pragma unroll
        for (int c = 0; c < 8; ++c) {
            const int k0 = (c << 7) + (ii << 3);
            const v8s p = *(const v8s*)&Ph[qq][k0];
            float4 o0, o1;
            o0.x = bf2f((unsigned short)p[0]) * inv;
            o0.y = bf2f((unsigned short)p[1]) * inv;
            o0.z = bf2f((unsigned short)p[2]) * inv;
            o0.w = bf2f((unsigned short)p[3]) * inv;
            o1.x = bf2f((unsigned short)p[4]) * inv;
            o1.y = bf2f((unsigned short)p[5]) * inv;
            o1.z = bf2f((unsigned short)p[6]) * inv;
            o1.w = bf2f((unsigned short)p[7]) * inv;
            *(float4*)(arow + k0)     = o0;
            *(float4*)(arow + k0 + 4) = o1;
        }
    }

    // ---- Phase B: context = (P V) * inv ----
    const int qf2 = w & 1, df = w >> 1;   // wave -> C fragment (16q x 16d)
    v4f accp = {0.f, 0.f, 0.f, 0.f};
    for (int kt = 0; kt < 8; ++kt) {
        __syncthreads();  // Vt overlays K buffers / prev tile reads done
        #pragma unroll
        for (int i = 0; i < 4; ++i) {
            const int f = tid + (i << 9);
            const int row = f >> 4, c4 = (f & 15) << 2;
            const float4 vv = *(const float4*)(Vb + (size_t)((kt << 7) + row) * Dn + c4);
            Vt[c4 + 0][row] = f2bf(vv.x);
            Vt[c4 + 1][row] = f2bf(vv.y);
            Vt[c4 + 2][row] = f2bf(vv.z);
            Vt[c4 + 3][row] = f2bf(vv.w);
        }
        __syncthreads();
        #pragma unroll
        for (int kk = 0; kk < 4; ++kk) {
            const int kb = kk << 5;
            const v8s a = *(const v8s*)&Ph[(qf2 << 4) + fr][(kt << 7) + kb + (g << 3)];
            const v8s b = *(const v8s*)&Vt[(df << 4) + fr][kb + (g << 3)];
            accp = __builtin_amdgcn_mfma_f32_16x16x32_bf16(a, b, accp, 0, 0, 0);
        }
    }
    #pragma unroll
    for (int r = 0; r < 4; ++r) {
        const int q = (qf2 << 4) + (g << 2) + r;
        Cb[(size_t)q * Dn + (df << 4) + fr] = accp[r] * invL[q];
    }
}

extern "C" void kernel_launch(void* const* d_in, const int* in_sizes, int n_in,
                              void* d_out, int out_size, void* d_ws, size_t ws_size,
                              hipStream_t stream) {
    const float* Q    = (const float*)d_in[0];
    const float* K    = (const float*)d_in[1];
    const float* V    = (const float*)d_in[2];
    const int*   mask = (const int*)d_in[3];

    float* ctx  = (float*)d_out;                           // (B,H,S,D)
    float* attn = (float*)d_out + (size_t)128 * Sn * Dn;   // (B,H,S,S)

    fused_attn<<<128 * 32, 512, 0, stream>>>(Q, K, V, mask, attn, ctx);
}

// Round 3
// 502.327 us; speedup vs baseline: 1.3211x; 1.3211x over previous
//
#include <hip/hip_runtime.h>

#define Sn 1024
#define Dn 64
#define PH_LD 1048   // ushorts/row: 524 dw ≡ 12 (mod 32), rows 16B-aligned -> conflict-min b128
#define K_LD 72      // ushorts/row: 36 dw ≡ 4 (mod 32), rows 16B-aligned
#define V_LD 72

typedef short v8s __attribute__((ext_vector_type(8)));
typedef float v4f __attribute__((ext_vector_type(4)));

__device__ __forceinline__ unsigned short f2bf(float x) {
    union { float f; unsigned u; } v; v.f = x;
    return (unsigned short)((v.u + 0x7FFFu + ((v.u >> 16) & 1u)) >> 16);
}
__device__ __forceinline__ float bf2f(unsigned short h) {
    union { float f; unsigned u; } v; v.u = ((unsigned)h) << 16;
    return v.f;
}
__device__ __forceinline__ void split2(float x, unsigned short& h, unsigned short& l) {
    unsigned short hs = f2bf(x);
    h = hs; l = f2bf(x - bf2f(hs));
}

// Block: 16 q-rows of one (b,h), 256 threads (4 waves), 3 blocks/CU.
// Phase A: S^T = mfma(K,Q) hi/lo bf16 split; lane(fr,g) holds P[q=fr][k=4g+r].
// Phase B: ctx = (P V)*inv via bf16 MFMA. Then attn = P*inv written coalesced.
__global__ __launch_bounds__(256, 3) void fused_attn(
    const float* __restrict__ Q, const float* __restrict__ K,
    const float* __restrict__ V, const int* __restrict__ M,
    float* __restrict__ attnO, float* __restrict__ ctxO)
{
    __shared__ unsigned short Ph[16][PH_LD];                       // exp(S) bf16
    __shared__ __align__(16) unsigned short Kraw[2 * 64 * K_LD];   // Khi|Klo, reused as Vt
    __shared__ float rsumW[4][16];
    __shared__ float invL[16];

    unsigned short (*Khi)[K_LD] = (unsigned short (*)[K_LD])Kraw;
    unsigned short (*Klo)[K_LD] = (unsigned short (*)[K_LD])(Kraw + 64 * K_LD);
    unsigned short (*Vt)[V_LD]  = (unsigned short (*)[V_LD])Kraw;  // [d][k-in-tile]

    const int tid  = threadIdx.x;
    const int lane = tid & 63;
    const int w    = tid >> 6;    // wave 0..3
    const int fr   = lane & 15;
    const int g    = lane >> 4;   // 0..3

    const int bh = blockIdx.x >> 6;
    const int q0 = (blockIdx.x & 63) << 4;

    const float* Qb = Q + (size_t)bh * Sn * Dn + (size_t)q0 * Dn;
    const float* Kb = K + (size_t)bh * Sn * Dn;
    const float* Vb = V + (size_t)bh * Sn * Dn;
    const int*   Mb = M + (size_t)bh * Sn * Sn + (size_t)q0 * Sn;
    float*       Ab = attnO + (size_t)bh * Sn * Sn + (size_t)q0 * Sn;
    float*       Cb = ctxO  + (size_t)bh * Sn * Dn + (size_t)q0 * Dn;

    // ---- Q B-fragments direct from global (tiny, once) ----
    v8s qh0, qh1, ql0, ql1;
    {
        const float* qp = Qb + fr * Dn + (g << 3);
        float x0[8], x1[8];
        *(float4*)&x0[0] = *(const float4*)qp;
        *(float4*)&x0[4] = *(const float4*)(qp + 4);
        *(float4*)&x1[0] = *(const float4*)(qp + 32);
        *(float4*)&x1[4] = *(const float4*)(qp + 36);
        #pragma unroll
        for (int i = 0; i < 8; ++i) {
            unsigned short hh, ll;
            split2(x0[i], hh, ll); qh0[i] = (short)hh; ql0[i] = (short)ll;
            split2(x1[i], hh, ll); qh1[i] = (short)hh; ql1[i] = (short)ll;
        }
    }

    const int srow = tid >> 4;          // staging row base (+16*i)
    const int sc4  = (tid & 15) << 2;   // staging col (4 floats)

    const int* mp = Mb + (size_t)fr * Sn + (w << 4) + (g << 2);
    int4 mv = *(const int4*)mp;         // mask for kt=0

    // preload K tile 0 into regs
    float4 ka[4];
    #pragma unroll
    for (int i = 0; i < 4; ++i)
        ka[i] = *(const float4*)(Kb + (size_t)(srow + (i << 4)) * Dn + sc4);

    float rs = 0.f;

    // ---- Phase A: 16 k-tiles of 64 ----
    for (int kt = 0; kt < 16; ++kt) {
        __syncthreads();   // prev tile's frag reads complete
        // prefetch next K tile (regs) — overlaps split+write+MFMA below
        float4 kb[4];
        if (kt < 15) {
            const float* kn = Kb + (size_t)((kt + 1) << 6) * Dn;
            #pragma unroll
            for (int i = 0; i < 4; ++i)
                kb[i] = *(const float4*)(kn + (size_t)(srow + (i << 4)) * Dn + sc4);
        }
        int4 mnext = mv;
        if (kt < 15) mnext = *(const int4*)(mp + ((kt + 1) << 6));

        // split current K tile into LDS hi/lo
        #pragma unroll
        for (int i = 0; i < 4; ++i) {
            const int row = srow + (i << 4);
            ushort4 hv, lv;
            split2(ka[i].x, hv.x, lv.x); split2(ka[i].y, hv.y, lv.y);
            split2(ka[i].z, hv.z, lv.z); split2(ka[i].w, hv.w, lv.w);
            *(ushort4*)&Khi[row][sc4] = hv;
            *(ushort4*)&Klo[row][sc4] = lv;
        }
        __syncthreads();

        const int krow = (w << 4) + fr;
        const v8s kh0 = *(const v8s*)&Khi[krow][(g << 3)];
        const v8s kh1 = *(const v8s*)&Khi[krow][32 + (g << 3)];
        const v8s kl0 = *(const v8s*)&Klo[krow][(g << 3)];
        const v8s kl1 = *(const v8s*)&Klo[krow][32 + (g << 3)];

        v4f acc = {0.f, 0.f, 0.f, 0.f};
        acc = __builtin_amdgcn_mfma_f32_16x16x32_bf16(kh0, qh0, acc, 0, 0, 0);
        acc = __builtin_amdgcn_mfma_f32_16x16x32_bf16(kh1, qh1, acc, 0, 0, 0);
        acc = __builtin_amdgcn_mfma_f32_16x16x32_bf16(kl0, qh0, acc, 0, 0, 0);
        acc = __builtin_amdgcn_mfma_f32_16x16x32_bf16(kl1, qh1, acc, 0, 0, 0);
        acc = __builtin_amdgcn_mfma_f32_16x16x32_bf16(kh0, ql0, acc, 0, 0, 0);
        acc = __builtin_amdgcn_mfma_f32_16x16x32_bf16(kh1, ql1, acc, 0, 0, 0);

        const float e0 = mv.x ? 1.0f : __expf(acc[0]);
        const float e1 = mv.y ? 1.0f : __expf(acc[1]);
        const float e2 = mv.z ? 1.0f : __expf(acc[2]);
        const float e3 = mv.w ? 1.0f : __expf(acc[3]);
        rs += (e0 + e1) + (e2 + e3);
        ushort4 pk;
        pk.x = f2bf(e0); pk.y = f2bf(e1); pk.z = f2bf(e2); pk.w = f2bf(e3);
        *(ushort4*)&Ph[fr][(kt << 6) + (w << 4) + (g << 2)] = pk;   // aligned b64

        mv = mnext;
        #pragma unroll
        for (int i = 0; i < 4; ++i) ka[i] = kb[i];
    }

    // ---- row-sum reduce: over g-groups, then waves ----
    rs += __shfl_xor(rs, 16);
    rs += __shfl_xor(rs, 32);
    if (g == 0) rsumW[w][fr] = rs;
    __syncthreads();
    if (tid < 16) {
        const float s = rsumW[0][tid] + rsumW[1][tid] + rsumW[2][tid] + rsumW[3][tid];
        invL[tid] = 1.0f / s;
    }
    __syncthreads();

    // ---- Phase B: ctx = (P V) * inv ----
    const int dcol = (w << 4) + fr;
    float4 va[4];
    #pragma unroll
    for (int i = 0; i < 4; ++i)
        va[i] = *(const float4*)(Vb + (size_t)(srow + (i << 4)) * Dn + sc4);

    v4f accp = {0.f, 0.f, 0.f, 0.f};
    for (int kt = 0; kt < 16; ++kt) {
        __syncthreads();   // prev Vt reads complete (also guards Khi/Klo overlay)
        float4 vb[4];
        if (kt < 15) {
            const float* vn = Vb + (size_t)((kt + 1) << 6) * Dn;
            #pragma unroll
            for (int i = 0; i < 4; ++i)
                vb[i] = *(const float4*)(vn + (size_t)(srow + (i << 4)) * Dn + sc4);
        }
        #pragma unroll
        for (int i = 0; i < 4; ++i) {
            const int row = srow + (i << 4);   // k-row in tile
            Vt[sc4 + 0][row] = f2bf(va[i].x);
            Vt[sc4 + 1][row] = f2bf(va[i].y);
            Vt[sc4 + 2][row] = f2bf(va[i].z);
            Vt[sc4 + 3][row] = f2bf(va[i].w);
        }
        __syncthreads();

        #pragma unroll
        for (int c = 0; c < 2; ++c) {
            const int kc = (kt << 6) + (c << 5);
            const v8s a = *(const v8s*)&Ph[fr][kc + (g << 3)];          // P[q=fr][k]
            const v8s b = *(const v8s*)&Vt[dcol][(c << 5) + (g << 3)];  // V[k][d=dcol]
            accp = __builtin_amdgcn_mfma_f32_16x16x32_bf16(a, b, accp, 0, 0, 0);
        }
        #pragma unroll
        for (int i = 0; i < 4; ++i) va[i] = vb[i];
    }
    #pragma unroll
    for (int r = 0; r < 4; ++r) {
        const int q = (g << 2) + r;
        Cb[(size_t)q * Dn + dcol] = accp[r] * invL[q];
    }

    // ---- write normalized attn (coalesced, conflict-free) ----
    {
        const int qq = tid >> 4, ii = tid & 15;
        const float inv = invL[qq];
        float* arow = Ab + (size_t)qq * Sn;
        #pragma unroll
        for (int c = 0; c < 16; ++c) {
            const int k0 = (c << 6) + (ii << 2);
            const ushort4 p = *(const ushort4*)&Ph[qq][k0];
            float4 o;
            o.x = bf2f(p.x) * inv; o.y = bf2f(p.y) * inv;
            o.z = bf2f(p.z) * inv; o.w = bf2f(p.w) * inv;
            *(float4*)(arow + k0) = o;
        }
    }
}

extern "C" void kernel_launch(void* const* d_in, const int* in_sizes, int n_in,
                              void* d_out, int out_size, void* d_ws, size_t ws_size,
                              hipStream_t stream) {
    const float* Q    = (const float*)d_in[0];
    const float* K    = (const float*)d_in[1];
    const float* V    = (const float*)d_in[2];
    const int*   mask = (const int*)d_in[3];

    float* ctx  = (float*)d_out;                           // (B,H,S,D)
    float* attn = (float*)d_out + (size_t)128 * Sn * Dn;   // (B,H,S,S)

    fused_attn<<<128 * 64, 256, 0, stream>>>(Q, K, V, mask, attn, ctx);
}

// Round 4
// 415.287 us; speedup vs baseline: 1.5979x; 1.2096x over previous
//
#include <hip/hip_runtime.h>

#define Sn 1024
#define Dn 64
#define PH_LD 1032   // ushorts/row: 516 dw ≡ 4 (mod 32) -> conflict-free b64 write / b128 read / b64 read
#define K_LD 72      // ushorts/row: 36 dw ≡ 4 (mod 32)  -> conflict-free b128 stage + frag reads
#define V_LD 72

typedef short v8s __attribute__((ext_vector_type(8)));
typedef unsigned short v8u __attribute__((ext_vector_type(8)));
typedef float v4f __attribute__((ext_vector_type(4)));

__device__ __forceinline__ unsigned short f2bf(float x) {
    union { float f; unsigned u; } v; v.f = x;
    return (unsigned short)((v.u + 0x7FFFu + ((v.u >> 16) & 1u)) >> 16);
}
__device__ __forceinline__ float bf2f(unsigned short h) {
    union { float f; unsigned u; } v; v.u = ((unsigned)h) << 16;
    return v.f;
}
__device__ __forceinline__ void split2(float x, unsigned short& h, unsigned short& l) {
    unsigned short hs = f2bf(x);
    h = hs; l = f2bf(x - bf2f(hs));
}

// ---------------- prep: K -> Khi/Klo bf16 (flat) ----------------
__global__ __launch_bounds__(256) void prep_k(const float* __restrict__ K,
    unsigned short* __restrict__ Khi, unsigned short* __restrict__ Klo)
{
    const size_t i = (((size_t)blockIdx.x << 8) + threadIdx.x) << 3;
    float x[8];
    *(float4*)&x[0] = *(const float4*)(K + i);
    *(float4*)&x[4] = *(const float4*)(K + i + 4);
    v8u h, l;
    #pragma unroll
    for (int j = 0; j < 8; ++j) {
        unsigned short hh, ll;
        split2(x[j], hh, ll);
        h[j] = hh; l[j] = ll;
    }
    *(v8u*)(Khi + i) = h;
    *(v8u*)(Klo + i) = l;
}

// ---------------- prep: V -> V^T bf16, per (bh, 64-k tile) ----------------
__global__ __launch_bounds__(256) void prep_v(const float* __restrict__ V,
    unsigned short* __restrict__ VT)
{
    __shared__ float Ts[64][65];
    const int bh = blockIdx.x >> 4, kt = blockIdx.x & 15;
    const int t = threadIdx.x;
    {
        const int r = t >> 2, cs = (t & 3) << 4;
        const float* src = V + ((size_t)bh * Sn + (kt << 6) + r) * Dn + cs;
        const float4 a = ((const float4*)src)[0];
        const float4 b = ((const float4*)src)[1];
        const float4 c = ((const float4*)src)[2];
        const float4 d = ((const float4*)src)[3];
        Ts[r][cs + 0] = a.x;  Ts[r][cs + 1] = a.y;  Ts[r][cs + 2] = a.z;  Ts[r][cs + 3] = a.w;
        Ts[r][cs + 4] = b.x;  Ts[r][cs + 5] = b.y;  Ts[r][cs + 6] = b.z;  Ts[r][cs + 7] = b.w;
        Ts[r][cs + 8] = c.x;  Ts[r][cs + 9] = c.y;  Ts[r][cs + 10] = c.z; Ts[r][cs + 11] = c.w;
        Ts[r][cs + 12] = d.x; Ts[r][cs + 13] = d.y; Ts[r][cs + 14] = d.z; Ts[r][cs + 15] = d.w;
    }
    __syncthreads();
    {
        const int dd = t >> 2, ks = (t & 3) << 4;
        unsigned short* dst = VT + ((size_t)bh << 16) + ((size_t)dd << 10) + (kt << 6) + ks;
        v8u o0, o1;
        #pragma unroll
        for (int j = 0; j < 8; ++j) o0[j] = f2bf(Ts[ks + j][dd]);
        #pragma unroll
        for (int j = 0; j < 8; ++j) o1[j] = f2bf(Ts[ks + 8 + j][dd]);
        *(v8u*)dst = o0;
        *(v8u*)(dst + 8) = o1;
    }
}

// ---------------- fused attention (pre-converted K/V) ----------------
// Block: 16 q-rows, 256 threads (4 waves), 3 blocks/CU.
// Phase A: S^T = mfma(K,Q) 3-term hi/lo; lane(fr,g,w) holds P[q=fr][k=64kt+16w+4g+r].
// Phase B: ctx = (P V)*inv. Then attn = P*inv coalesced.
__global__ __launch_bounds__(256, 3) void fused_attn_p(
    const unsigned short* __restrict__ KhiG, const unsigned short* __restrict__ KloG,
    const unsigned short* __restrict__ VTG,  const float* __restrict__ Q,
    const int* __restrict__ M, float* __restrict__ attnO, float* __restrict__ ctxO)
{
    __shared__ unsigned short Ph[16][PH_LD];
    __shared__ __align__(16) unsigned short Kraw[2 * 64 * K_LD];
    __shared__ float rsumW[4][16];
    __shared__ float invL[16];

    unsigned short (*Khi)[K_LD] = (unsigned short (*)[K_LD])Kraw;
    unsigned short (*Klo)[K_LD] = (unsigned short (*)[K_LD])(Kraw + 64 * K_LD);
    unsigned short (*Vt)[V_LD]  = (unsigned short (*)[V_LD])Kraw;

    const int tid  = threadIdx.x;
    const int lane = tid & 63;
    const int w    = tid >> 6;
    const int fr   = lane & 15;
    const int g    = lane >> 4;

    const int bh = blockIdx.x >> 6;
    const int q0 = (blockIdx.x & 63) << 4;

    const float* Qb = Q + (size_t)bh * Sn * Dn + (size_t)q0 * Dn;
    const int*   Mb = M + (size_t)bh * Sn * Sn + (size_t)q0 * Sn;
    float*       Ab = attnO + (size_t)bh * Sn * Sn + (size_t)q0 * Sn;
    float*       Cb = ctxO  + (size_t)bh * Sn * Dn + (size_t)q0 * Dn;
    const unsigned short* KhiB = KhiG + ((size_t)bh << 16);
    const unsigned short* KloB = KloG + ((size_t)bh << 16);
    const unsigned short* VTB  = VTG  + ((size_t)bh << 16);

    // Q B-fragments: global float4 + in-reg split (tiny, once per block)
    v8s qh0, qh1, ql0, ql1;
    {
        const float* qp = Qb + fr * Dn + (g << 3);
        float x0[8], x1[8];
        *(float4*)&x0[0] = *(const float4*)qp;
        *(float4*)&x0[4] = *(const float4*)(qp + 4);
        *(float4*)&x1[0] = *(const float4*)(qp + 32);
        *(float4*)&x1[4] = *(const float4*)(qp + 36);
        #pragma unroll
        for (int i = 0; i < 8; ++i) {
            unsigned short hh, ll;
            split2(x0[i], hh, ll); qh0[i] = (short)hh; ql0[i] = (short)ll;
            split2(x1[i], hh, ll); qh1[i] = (short)hh; ql1[i] = (short)ll;
        }
    }

    const int srow = tid >> 2;          // 0..63: k-row (A) / d-row (B)
    const int sseg = (tid & 3) << 4;    // ushort col: 0/16/32/48

    const int* mp = Mb + (size_t)fr * Sn + (w << 4) + (g << 2);
    int4 mv = *(const int4*)mp;

    // preload K tile 0 (bf16 hi/lo) into regs
    uint4 ch0, ch1, cl0, cl1;
    {
        const uint4* ph = (const uint4*)(KhiB + (size_t)srow * Dn + sseg);
        const uint4* pl = (const uint4*)(KloB + (size_t)srow * Dn + sseg);
        ch0 = ph[0]; ch1 = ph[1]; cl0 = pl[0]; cl1 = pl[1];
    }

    float rs = 0.f;

    // ---- Phase A ----
    for (int kt = 0; kt < 16; ++kt) {
        __syncthreads();   // prev tile's frag reads complete
        *(uint4*)&Khi[srow][sseg]     = ch0;
        *(uint4*)&Khi[srow][sseg + 8] = ch1;
        *(uint4*)&Klo[srow][sseg]     = cl0;
        *(uint4*)&Klo[srow][sseg + 8] = cl1;

        int4 mnext = mv;
        if (kt < 15) {
            const uint4* ph = (const uint4*)(KhiB + (size_t)((kt + 1) * 64 + srow) * Dn + sseg);
            const uint4* pl = (const uint4*)(KloB + (size_t)((kt + 1) * 64 + srow) * Dn + sseg);
            ch0 = ph[0]; ch1 = ph[1]; cl0 = pl[0]; cl1 = pl[1];
            mnext = *(const int4*)(mp + ((kt + 1) << 6));
        }
        __syncthreads();

        const int krow = (w << 4) + fr;
        const v8s kh0 = *(const v8s*)&Khi[krow][(g << 3)];
        const v8s kh1 = *(const v8s*)&Khi[krow][32 + (g << 3)];
        const v8s kl0 = *(const v8s*)&Klo[krow][(g << 3)];
        const v8s kl1 = *(const v8s*)&Klo[krow][32 + (g << 3)];

        v4f acc = {0.f, 0.f, 0.f, 0.f};
        acc = __builtin_amdgcn_mfma_f32_16x16x32_bf16(kh0, qh0, acc, 0, 0, 0);
        acc = __builtin_amdgcn_mfma_f32_16x16x32_bf16(kh1, qh1, acc, 0, 0, 0);
        acc = __builtin_amdgcn_mfma_f32_16x16x32_bf16(kl0, qh0, acc, 0, 0, 0);
        acc = __builtin_amdgcn_mfma_f32_16x16x32_bf16(kl1, qh1, acc, 0, 0, 0);
        acc = __builtin_amdgcn_mfma_f32_16x16x32_bf16(kh0, ql0, acc, 0, 0, 0);
        acc = __builtin_amdgcn_mfma_f32_16x16x32_bf16(kh1, ql1, acc, 0, 0, 0);

        const float e0 = mv.x ? 1.0f : __expf(acc[0]);
        const float e1 = mv.y ? 1.0f : __expf(acc[1]);
        const float e2 = mv.z ? 1.0f : __expf(acc[2]);
        const float e3 = mv.w ? 1.0f : __expf(acc[3]);
        rs += (e0 + e1) + (e2 + e3);
        ushort4 pk;
        pk.x = f2bf(e0); pk.y = f2bf(e1); pk.z = f2bf(e2); pk.w = f2bf(e3);
        *(ushort4*)&Ph[fr][(kt << 6) + (w << 4) + (g << 2)] = pk;

        mv = mnext;
    }

    // preload V tile 0 early (hides latency under the reduction)
    uint4 cv0, cv1;
    {
        const uint4* pv = (const uint4*)(VTB + ((size_t)srow << 10) + sseg);
        cv0 = pv[0]; cv1 = pv[1];
    }

    // ---- row-sum reduce ----
    rs += __shfl_xor(rs, 16);
    rs += __shfl_xor(rs, 32);
    if (g == 0) rsumW[w][fr] = rs;
    __syncthreads();
    if (tid < 16) {
        const float s = rsumW[0][tid] + rsumW[1][tid] + rsumW[2][tid] + rsumW[3][tid];
        invL[tid] = 1.0f / s;
    }

    // ---- Phase B: ctx = (P V) * inv ----
    const int dcol = (w << 4) + fr;
    v4f accp = {0.f, 0.f, 0.f, 0.f};
    for (int kt = 0; kt < 16; ++kt) {
        __syncthreads();   // prev Vt reads done (and invL ready on first iter)
        *(uint4*)&Vt[srow][sseg]     = cv0;
        *(uint4*)&Vt[srow][sseg + 8] = cv1;
        if (kt < 15) {
            const uint4* pv = (const uint4*)(VTB + ((size_t)srow << 10) + ((kt + 1) << 6) + sseg);
            cv0 = pv[0]; cv1 = pv[1];
        }
        __syncthreads();

        #pragma unroll
        for (int c = 0; c < 2; ++c) {
            const v8s a = *(const v8s*)&Ph[fr][(kt << 6) + (c << 5) + (g << 3)];
            const v8s b = *(const v8s*)&Vt[dcol][(c << 5) + (g << 3)];
            accp = __builtin_amdgcn_mfma_f32_16x16x32_bf16(a, b, accp, 0, 0, 0);
        }
    }
    #pragma unroll
    for (int r = 0; r < 4; ++r) {
        const int q = (g << 2) + r;
        Cb[(size_t)q * Dn + dcol] = accp[r] * invL[q];
    }

    // ---- write normalized attn ----
    {
        const int qq = tid >> 4, ii = tid & 15;
        const float inv = invL[qq];
        float* arow = Ab + (size_t)qq * Sn;
        #pragma unroll
        for (int c = 0; c < 16; ++c) {
            const int k0 = (c << 6) + (ii << 2);
            const ushort4 p = *(const ushort4*)&Ph[qq][k0];
            float4 o;
            o.x = bf2f(p.x) * inv; o.y = bf2f(p.y) * inv;
            o.z = bf2f(p.z) * inv; o.w = bf2f(p.w) * inv;
            *(float4*)(arow + k0) = o;
        }
    }
}

// ---------------- fallback (round-3 kernel, in-kernel split) ----------------
__global__ __launch_bounds__(256, 3) void fused_attn_fb(
    const float* __restrict__ Q, const float* __restrict__ K,
    const float* __restrict__ V, const int* __restrict__ M,
    float* __restrict__ attnO, float* __restrict__ ctxO)
{
    __shared__ unsigned short Ph[16][1048];
    __shared__ __align__(16) unsigned short Kraw[2 * 64 * K_LD];
    __shared__ float rsumW[4][16];
    __shared__ float invL[16];

    unsigned short (*Khi)[K_LD] = (unsigned short (*)[K_LD])Kraw;
    unsigned short (*Klo)[K_LD] = (unsigned short (*)[K_LD])(Kraw + 64 * K_LD);
    unsigned short (*Vt)[V_LD]  = (unsigned short (*)[V_LD])Kraw;

    const int tid  = threadIdx.x;
    const int lane = tid & 63;
    const int w    = tid >> 6;
    const int fr   = lane & 15;
    const int g    = lane >> 4;

    const int bh = blockIdx.x >> 6;
    const int q0 = (blockIdx.x & 63) << 4;

    const float* Qb = Q + (size_t)bh * Sn * Dn + (size_t)q0 * Dn;
    const float* Kb = K + (size_t)bh * Sn * Dn;
    const float* Vb = V + (size_t)bh * Sn * Dn;
    const int*   Mb = M + (size_t)bh * Sn * Sn + (size_t)q0 * Sn;
    float*       Ab = attnO + (size_t)bh * Sn * Sn + (size_t)q0 * Sn;
    float*       Cb = ctxO  + (size_t)bh * Sn * Dn + (size_t)q0 * Dn;

    v8s qh0, qh1, ql0, ql1;
    {
        const float* qp = Qb + fr * Dn + (g << 3);
        float x0[8], x1[8];
        *(float4*)&x0[0] = *(const float4*)qp;
        *(float4*)&x0[4] = *(const float4*)(qp + 4);
        *(float4*)&x1[0] = *(const float4*)(qp + 32);
        *(float4*)&x1[4] = *(const float4*)(qp + 36);
        #pragma unroll
        for (int i = 0; i < 8; ++i) {
            unsigned short hh, ll;
            split2(x0[i], hh, ll); qh0[i] = (short)hh; ql0[i] = (short)ll;
            split2(x1[i], hh, ll); qh1[i] = (short)hh; ql1[i] = (short)ll;
        }
    }

    const int srow = tid >> 4;
    const int sc4  = (tid & 15) << 2;

    const int* mp = Mb + (size_t)fr * Sn + (w << 4) + (g << 2);
    int4 mv = *(const int4*)mp;

    float4 ka[4];
    #pragma unroll
    for (int i = 0; i < 4; ++i)
        ka[i] = *(const float4*)(Kb + (size_t)(srow + (i << 4)) * Dn + sc4);

    float rs = 0.f;

    for (int kt = 0; kt < 16; ++kt) {
        __syncthreads();
        float4 kb[4];
        if (kt < 15) {
            const float* kn = Kb + (size_t)((kt + 1) << 6) * Dn;
            #pragma unroll
            for (int i = 0; i < 4; ++i)
                kb[i] = *(const float4*)(kn + (size_t)(srow + (i << 4)) * Dn + sc4);
        }
        int4 mnext = mv;
        if (kt < 15) mnext = *(const int4*)(mp + ((kt + 1) << 6));

        #pragma unroll
        for (int i = 0; i < 4; ++i) {
            const int row = srow + (i << 4);
            ushort4 hv, lv;
            split2(ka[i].x, hv.x, lv.x); split2(ka[i].y, hv.y, lv.y);
            split2(ka[i].z, hv.z, lv.z); split2(ka[i].w, hv.w, lv.w);
            *(ushort4*)&Khi[row][sc4] = hv;
            *(ushort4*)&Klo[row][sc4] = lv;
        }
        __syncthreads();

        const int krow = (w << 4) + fr;
        const v8s kh0 = *(const v8s*)&Khi[krow][(g << 3)];
        const v8s kh1 = *(const v8s*)&Khi[krow][32 + (g << 3)];
        const v8s kl0 = *(const v8s*)&Klo[krow][(g << 3)];
        const v8s kl1 = *(const v8s*)&Klo[krow][32 + (g << 3)];

        v4f acc = {0.f, 0.f, 0.f, 0.f};
        acc = __builtin_amdgcn_mfma_f32_16x16x32_bf16(kh0, qh0, acc, 0, 0, 0);
        acc = __builtin_amdgcn_mfma_f32_16x16x32_bf16(kh1, qh1, acc, 0, 0, 0);
        acc = __builtin_amdgcn_mfma_f32_16x16x32_bf16(kl0, qh0, acc, 0, 0, 0);
        acc = __builtin_amdgcn_mfma_f32_16x16x32_bf16(kl1, qh1, acc, 0, 0, 0);
        acc = __builtin_amdgcn_mfma_f32_16x16x32_bf16(kh0, ql0, acc, 0, 0, 0);
        acc = __builtin_amdgcn_mfma_f32_16x16x32_bf16(kh1, ql1, acc, 0, 0, 0);

        const float e0 = mv.x ? 1.0f : __expf(acc[0]);
        const float e1 = mv.y ? 1.0f : __expf(acc[1]);
        const float e2 = mv.z ? 1.0f : __expf(acc[2]);
        const float e3 = mv.w ? 1.0f : __expf(acc[3]);
        rs += (e0 + e1) + (e2 + e3);
        ushort4 pk;
        pk.x = f2bf(e0); pk.y = f2bf(e1); pk.z = f2bf(e2); pk.w = f2bf(e3);
        *(ushort4*)&Ph[fr][(kt << 6) + (w << 4) + (g << 2)] = pk;

        mv = mnext;
        #pragma unroll
        for (int i = 0; i < 4; ++i) ka[i] = kb[i];
    }

    rs += __shfl_xor(rs, 16);
    rs += __shfl_xor(rs, 32);
    if (g == 0) rsumW[w][fr] = rs;
    __syncthreads();
    if (tid < 16) {
        const float s = rsumW[0][tid] + rsumW[1][tid] + rsumW[2][tid] + rsumW[3][tid];
        invL[tid] = 1.0f / s;
    }
    __syncthreads();

    const int dcol = (w << 4) + fr;
    float4 va[4];
    #pragma unroll
    for (int i = 0; i < 4; ++i)
        va[i] = *(const float4*)(Vb + (size_t)(srow + (i << 4)) * Dn + sc4);

    v4f accp = {0.f, 0.f, 0.f, 0.f};
    for (int kt = 0; kt < 16; ++kt) {
        __syncthreads();
        float4 vb[4];
        if (kt < 15) {
            const float* vn = Vb + (size_t)((kt + 1) << 6) * Dn;
            #pragma unroll
            for (int i = 0; i < 4; ++i)
                vb[i] = *(const float4*)(vn + (size_t)(srow + (i << 4)) * Dn + sc4);
        }
        #pragma unroll
        for (int i = 0; i < 4; ++i) {
            const int row = srow + (i << 4);
            Vt[sc4 + 0][row] = f2bf(va[i].x);
            Vt[sc4 + 1][row] = f2bf(va[i].y);
            Vt[sc4 + 2][row] = f2bf(va[i].z);
            Vt[sc4 + 3][row] = f2bf(va[i].w);
        }
        __syncthreads();

        #pragma unroll
        for (int c = 0; c < 2; ++c) {
            const int kc = (kt << 6) + (c << 5);
            const v8s a = *(const v8s*)&Ph[fr][kc + (g << 3)];
            const v8s b = *(const v8s*)&Vt[dcol][(c << 5) + (g << 3)];
            accp = __builtin_amdgcn_mfma_f32_16x16x32_bf16(a, b, accp, 0, 0, 0);
        }
        #pragma unroll
        for (int i = 0; i < 4; ++i) va[i] = vb[i];
    }
    #pragma unroll
    for (int r = 0; r < 4; ++r) {
        const int q = (g << 2) + r;
        Cb[(size_t)q * Dn + dcol] = accp[r] * invL[q];
    }

    {
        const int qq = tid >> 4, ii = tid & 15;
        const float inv = invL[qq];
        float* arow = Ab + (size_t)qq * Sn;
        #pragma unroll
        for (int c = 0; c < 16; ++c) {
            const int k0 = (c << 6) + (ii << 2);
            const ushort4 p = *(const ushort4*)&Ph[qq][k0];
            float4 o;
            o.x = bf2f(p.x) * inv; o.y = bf2f(p.y) * inv;
            o.z = bf2f(p.z) * inv; o.w = bf2f(p.w) * inv;
            *(float4*)(arow + k0) = o;
        }
    }
}

extern "C" void kernel_launch(void* const* d_in, const int* in_sizes, int n_in,
                              void* d_out, int out_size, void* d_ws, size_t ws_size,
                              hipStream_t stream) {
    const float* Q    = (const float*)d_in[0];
    const float* K    = (const float*)d_in[1];
    const float* V    = (const float*)d_in[2];
    const int*   mask = (const int*)d_in[3];

    float* ctx  = (float*)d_out;                           // (B,H,S,D)
    float* attn = (float*)d_out + (size_t)128 * Sn * Dn;   // (B,H,S,S)

    const size_t NELEM = (size_t)128 * Sn * Dn;            // 8,388,608
    const size_t NEED  = NELEM * 2 * 3;                    // Khi + Klo + VT (bf16)

    if (ws_size >= NEED) {
        unsigned short* Khi = (unsigned short*)d_ws;
        unsigned short* Klo = Khi + NELEM;
        unsigned short* VT  = Klo + NELEM;
        prep_k<<<4096, 256, 0, stream>>>(K, Khi, Klo);
        prep_v<<<2048, 256, 0, stream>>>(V, VT);
        fused_attn_p<<<128 * 64, 256, 0, stream>>>(Khi, Klo, VT, Q, mask, attn, ctx);
    } else {
        fused_attn_fb<<<128 * 64, 256, 0, stream>>>(Q, K, V, mask, attn, ctx);
    }
}